// Round 6
// baseline (948.344 us; speedup 1.0000x reference)
//
#include <hip/hip_runtime.h>

#define NB 16
#define SEQ 4096
#define DIMC 1024
#define NH 16
#define DH 64
#define NC 64   // 64-row chunks per batch

// ws layout (floats) — R0 baseline layout:
#define OFF_Q    0          // [16][1024]          16384
#define OFF_WTIL 16384      // [16][16][1024]      262144
#define OFF_PMAX 278528     // [16][64][16]        16384
#define OFF_LC   294912     // [16][64][16]        16384
#define OFF_HO4  311296     // [4][16][1024]       65536
#define OFF_Y    376832     // [16][64][16][1024]  16777216
// total 17154048 floats = 68.6 MB

// ---------- kq: q[b][j] = x[b,0,:] . Wq[:,j]   (grid 16 jc x 16 b)
__global__ __launch_bounds__(256) void kq(const float* __restrict__ x,
                                          const float* __restrict__ Wq,
                                          float* __restrict__ qws) {
  const int jc = blockIdx.x, b = blockIdx.y, t = threadIdx.x;
  const int d = t & 63, g = t >> 6;
  const int j = jc * 64 + d;
  const float* x0 = x + (size_t)b * SEQ * DIMC;
  __shared__ float red[256];
  float a = 0.f;
  #pragma unroll 8
  for (int c = g * 256; c < g * 256 + 256; ++c)
    a = fmaf(x0[c], Wq[(size_t)c * DIMC + j], a);
  red[t] = a;
  __syncthreads();
  if (t < 64)
    qws[b * DIMC + jc * 64 + t] = red[t] + red[64 + t] + red[128 + t] + red[192 + t];
}

// ---------- kw: wtil[b][h][c] = 0.125 * Wk[c, h*64:h*64+64] . q[b, h*64:h*64+64]
// (RoPE cancels in q_rot . k_rot since both use the same per-head rotation.)
__global__ __launch_bounds__(256) void kw(const float* __restrict__ Wk,
                                          const float* __restrict__ qws,
                                          float* __restrict__ wtil) {
  const int cb = blockIdx.x, b = blockIdx.y, t = threadIdx.x;
  const int w = t >> 6, l = t & 63;
  float4 qreg[4];
  {
    const float4* q4 = (const float4*)(qws + b * DIMC + l * 16);
    #pragma unroll
    for (int i = 0; i < 4; ++i) qreg[i] = q4[i];
  }
  const int h = l >> 2;
  float* wt = wtil + ((size_t)b * NH + h) * DIMC;
  #pragma unroll 4
  for (int i = 0; i < 16; ++i) {
    const int c = cb * 64 + w * 16 + i;
    const float4* row = (const float4*)(Wk + (size_t)c * DIMC) + l * 4;
    float s = 0.f;
    #pragma unroll
    for (int k = 0; k < 4; ++k) {
      float4 rv = row[k];
      s = fmaf(rv.x, qreg[k].x, s); s = fmaf(rv.y, qreg[k].y, s);
      s = fmaf(rv.z, qreg[k].z, s); s = fmaf(rv.w, qreg[k].w, s);
    }
    s += __shfl_xor(s, 1);
    s += __shfl_xor(s, 2);
    if ((l & 3) == 0) wt[c] = s * 0.125f;
  }
}

__device__ __forceinline__ float dot16(const float4* xv, const float4* wv) {
  float s = 0.f;
  #pragma unroll
  for (int i = 0; i < 4; ++i) {
    s = fmaf(xv[i].x, wv[i].x, s); s = fmaf(xv[i].y, wv[i].y, s);
    s = fmaf(xv[i].z, wv[i].z, s); s = fmaf(xv[i].w, wv[i].w, s);
  }
  return s;
}

// ---------- kF: fused logits + online softmax + phat@x, x read ONCE from global.
// Block (nc, b), 256 thr. Four 16-row groups per 64-row chunk:
//  phase A: coalesced global x loads (kS pattern) -> dots+butterfly; wave w stages its
//           quarter of each row into xt LDS tile; online max/sum update (flash).
//  phase B: thread t owns col-quad t; rescale acc by exp(m_old-m_new); accumulate
//           p rows (LDS broadcast) times x rows (from xt).
// Writes y[b][nc][h][:] = sum_r exp(S-m_chunk)*x[r][:], pmax=m_chunk, Lc=sum exp.
__global__ __launch_bounds__(256, 2) void kF(const float* __restrict__ x,
                                             const float* __restrict__ wtil,
                                             float* __restrict__ y,
                                             float* __restrict__ pmax,
                                             float* __restrict__ Lc) {
  const int nc = blockIdx.x, b = blockIdx.y, t = threadIdx.x;
  const int w = t >> 6, l = t & 63;
  __shared__ float4 xt[16][256];  // 16-row x tile (64 KB)
  __shared__ float4 pl[16][4];    // p rows for current group [row][head-quad]
  __shared__ float4 esl[4];       // per head-quad rescale factor

  const float4* wt4 = (const float4*)wtil + ((size_t)b * NH + w * 4) * 256;
  float4 wv[4][4];
  #pragma unroll
  for (int h = 0; h < 4; ++h)
    #pragma unroll
    for (int i = 0; i < 4; ++i) wv[h][i] = wt4[h * 256 + i * 64 + l];

  const float4* x4 = (const float4*)x + ((size_t)b * SEQ + nc * 64) * 256;

  float4 acc[16];
  #pragma unroll
  for (int h = 0; h < 16; ++h) acc[h] = make_float4(0.f, 0.f, 0.f, 0.f);
  const float NEG = -1.0e30f;
  float4 m_run = make_float4(NEG, NEG, NEG, NEG);
  float4 l_run = make_float4(0.f, 0.f, 0.f, 0.f);

  for (int g = 0; g < 4; ++g) {
    float4 va = make_float4(NEG, NEG, NEG, NEG);  // lane j captures local row j
    float4 gm = make_float4(NEG, NEG, NEG, NEG);  // group max (wave-uniform)
    __syncthreads();  // xt/pl/esl safe to overwrite (prev group's phase B done)
    for (int j = 0; j < 16; j += 2) {
      const int r = g * 16 + j;
      float4 xa[4], xb[4];
      #pragma unroll
      for (int i = 0; i < 4; ++i) xa[i] = x4[(size_t)r * 256 + i * 64 + l];
      #pragma unroll
      for (int i = 0; i < 4; ++i) xb[i] = x4[(size_t)(r + 1) * 256 + i * 64 + l];
      // stage: wave w owns col-quads w*64..w*64+63 of each row (static select, no scratch)
      float4 sxa = (w == 0) ? xa[0] : (w == 1) ? xa[1] : (w == 2) ? xa[2] : xa[3];
      float4 sxb = (w == 0) ? xb[0] : (w == 1) ? xb[1] : (w == 2) ? xb[2] : xb[3];
      xt[j][w * 64 + l] = sxa;
      xt[j + 1][w * 64 + l] = sxb;
      float4 sa, sb;
      sa.x = dot16(xa, wv[0]); sa.y = dot16(xa, wv[1]);
      sa.z = dot16(xa, wv[2]); sa.w = dot16(xa, wv[3]);
      sb.x = dot16(xb, wv[0]); sb.y = dot16(xb, wv[1]);
      sb.z = dot16(xb, wv[2]); sb.w = dot16(xb, wv[3]);
      #pragma unroll
      for (int o = 1; o < 64; o <<= 1) {
        sa.x += __shfl_xor(sa.x, o); sa.y += __shfl_xor(sa.y, o);
        sa.z += __shfl_xor(sa.z, o); sa.w += __shfl_xor(sa.w, o);
        sb.x += __shfl_xor(sb.x, o); sb.y += __shfl_xor(sb.y, o);
        sb.z += __shfl_xor(sb.z, o); sb.w += __shfl_xor(sb.w, o);
      }
      gm.x = fmaxf(gm.x, fmaxf(sa.x, sb.x)); gm.y = fmaxf(gm.y, fmaxf(sa.y, sb.y));
      gm.z = fmaxf(gm.z, fmaxf(sa.z, sb.z)); gm.w = fmaxf(gm.w, fmaxf(sa.w, sb.w));
      if (l == j) va = sa;
      if (l == j + 1) va = sb;
    }
    // online update (per wave = heads 4w..4w+3); all values wave-uniform except va
    float4 m_new;
    m_new.x = fmaxf(m_run.x, gm.x); m_new.y = fmaxf(m_run.y, gm.y);
    m_new.z = fmaxf(m_run.z, gm.z); m_new.w = fmaxf(m_run.w, gm.w);
    float4 es;
    es.x = __expf(m_run.x - m_new.x); es.y = __expf(m_run.y - m_new.y);
    es.z = __expf(m_run.z - m_new.z); es.w = __expf(m_run.w - m_new.w);
    float4 pv;
    pv.x = __expf(va.x - m_new.x); pv.y = __expf(va.y - m_new.y);
    pv.z = __expf(va.z - m_new.z); pv.w = __expf(va.w - m_new.w);  // lanes>=16 -> 0
    float4 gs = pv;
    #pragma unroll
    for (int o = 1; o < 64; o <<= 1) {
      gs.x += __shfl_xor(gs.x, o); gs.y += __shfl_xor(gs.y, o);
      gs.z += __shfl_xor(gs.z, o); gs.w += __shfl_xor(gs.w, o);
    }
    l_run.x = fmaf(l_run.x, es.x, gs.x); l_run.y = fmaf(l_run.y, es.y, gs.y);
    l_run.z = fmaf(l_run.z, es.z, gs.z); l_run.w = fmaf(l_run.w, es.w, gs.w);
    m_run = m_new;
    if (l < 16) pl[l][w] = pv;
    if (l == 0) esl[w] = es;
    __syncthreads();
    // phase B: rescale + accumulate this group's 16 rows from xt
    {
      float4 e0 = esl[0], e1 = esl[1], e2 = esl[2], e3 = esl[3];
      #define RES(h, s) acc[h].x *= s; acc[h].y *= s; acc[h].z *= s; acc[h].w *= s
      RES(0, e0.x); RES(1, e0.y); RES(2, e0.z); RES(3, e0.w);
      RES(4, e1.x); RES(5, e1.y); RES(6, e1.z); RES(7, e1.w);
      RES(8, e2.x); RES(9, e2.y); RES(10, e2.z); RES(11, e2.w);
      RES(12, e3.x); RES(13, e3.y); RES(14, e3.z); RES(15, e3.w);
      #undef RES
    }
    for (int j = 0; j < 16; j += 2) {
      float4 xva = xt[j][t];
      float4 xvb = xt[j + 1][t];
      float4 a0 = pl[j][0], a1 = pl[j][1], a2 = pl[j][2], a3 = pl[j][3];
      float4 b0 = pl[j + 1][0], b1 = pl[j + 1][1], b2 = pl[j + 1][2], b3 = pl[j + 1][3];
      #define ACC(h, ev, xv) acc[h].x = fmaf(ev, xv.x, acc[h].x); acc[h].y = fmaf(ev, xv.y, acc[h].y); \
                             acc[h].z = fmaf(ev, xv.z, acc[h].z); acc[h].w = fmaf(ev, xv.w, acc[h].w)
      ACC(0, a0.x, xva); ACC(1, a0.y, xva); ACC(2, a0.z, xva); ACC(3, a0.w, xva);
      ACC(4, a1.x, xva); ACC(5, a1.y, xva); ACC(6, a1.z, xva); ACC(7, a1.w, xva);
      ACC(8, a2.x, xva); ACC(9, a2.y, xva); ACC(10, a2.z, xva); ACC(11, a2.w, xva);
      ACC(12, a3.x, xva); ACC(13, a3.y, xva); ACC(14, a3.z, xva); ACC(15, a3.w, xva);
      ACC(0, b0.x, xvb); ACC(1, b0.y, xvb); ACC(2, b0.z, xvb); ACC(3, b0.w, xvb);
      ACC(4, b1.x, xvb); ACC(5, b1.y, xvb); ACC(6, b1.z, xvb); ACC(7, b1.w, xvb);
      ACC(8, b2.x, xvb); ACC(9, b2.y, xvb); ACC(10, b2.z, xvb); ACC(11, b2.w, xvb);
      ACC(12, b3.x, xvb); ACC(13, b3.y, xvb); ACC(14, b3.z, xvb); ACC(15, b3.w, xvb);
      #undef ACC
    }
  }

  float4* y4 = (float4*)y + (((size_t)b * NC + nc) * NH) * 256;
  #pragma unroll
  for (int h = 0; h < 16; ++h) y4[h * 256 + t] = acc[h];
  if (l == 0) {
    ((float4*)(pmax + ((size_t)b * NC + nc) * NH))[w] = m_run;
    ((float4*)(Lc + ((size_t)b * NC + nc) * NH))[w] = l_run;
  }
}

// ---------- k_comb: per (cs,h,b): scale from pmax/Lc in-block, ysum over chunks, x Wv slice
__global__ __launch_bounds__(256) void k_comb(const float* __restrict__ y,
                                              const float* __restrict__ pmax,
                                              const float* __restrict__ Lc,
                                              const float* __restrict__ Wv,
                                              float* __restrict__ ho4) {
  const int cs = blockIdx.x, h = blockIdx.y, b = blockIdx.z, t = threadIdx.x;
  __shared__ float sc[NC];
  __shared__ float ylds[256];
  __shared__ float red[256];
  if (t < 64) {
    float mt = pmax[((size_t)b * NC + t) * NH + h];
    float lt = Lc[((size_t)b * NC + t) * NH + h];
    float M = mt;
    #pragma unroll
    for (int o = 1; o < 64; o <<= 1) M = fmaxf(M, __shfl_xor(M, o));
    float e = __expf(mt - M);
    float L = lt * e;
    #pragma unroll
    for (int o = 1; o < 64; o <<= 1) L += __shfl_xor(L, o);
    sc[t] = e / L;
  }
  __syncthreads();
  const int c = cs * 256 + t;
  float ysum = 0.f;
  #pragma unroll 8
  for (int s = 0; s < NC; ++s)
    ysum = fmaf(y[(((size_t)b * NC + s) * NH + h) * DIMC + c], sc[s], ysum);
  ylds[t] = ysum;
  __syncthreads();
  const int d = t & 63, g = t >> 6;
  float part = 0.f;
  #pragma unroll 4
  for (int k = 0; k < 64; ++k)
    part = fmaf(ylds[g * 64 + k],
                Wv[(size_t)(cs * 256 + g * 64 + k) * DIMC + h * DH + d], part);
  red[t] = part;
  __syncthreads();
  if (t < 64)
    ho4[((size_t)cs * NB + b) * DIMC + h * DH + t] =
        red[t] + red[64 + t] + red[128 + t] + red[192 + t];
}

// ---------- k_out: out[b, j] = (sum_cs ho4[cs][b][:]) . Wp[:, j] + bp[j]
__global__ __launch_bounds__(256) void k_out(const float* __restrict__ ho4,
                                             const float* __restrict__ Wp,
                                             const float* __restrict__ bp,
                                             float* __restrict__ out) {
  const int jc = blockIdx.x, b = blockIdx.y, t = threadIdx.x;
  __shared__ float hs[1024];
  __shared__ float red[256];
  for (int i = t; i < 1024; i += 256)
    hs[i] = ho4[(size_t)b * DIMC + i] + ho4[(size_t)(NB + b) * DIMC + i] +
            ho4[(size_t)(2 * NB + b) * DIMC + i] + ho4[(size_t)(3 * NB + b) * DIMC + i];
  __syncthreads();
  const int d = t & 63, g = t >> 6;
  const int j = jc * 64 + d;
  float a = 0.f;
  #pragma unroll 8
  for (int i = g * 256; i < g * 256 + 256; ++i)
    a = fmaf(hs[i], Wp[(size_t)i * DIMC + j], a);
  red[t] = a;
  __syncthreads();
  if (t < 64)
    out[(size_t)b * DIMC + jc * 64 + t] =
        red[t] + red[64 + t] + red[128 + t] + red[192 + t] + bp[jc * 64 + t];
}

extern "C" void kernel_launch(void* const* d_in, const int* in_sizes, int n_in,
                              void* d_out, int out_size, void* d_ws, size_t ws_size,
                              hipStream_t stream) {
  const float* x  = (const float*)d_in[0];
  const float* Wq = (const float*)d_in[1];
  const float* Wk = (const float*)d_in[2];
  const float* Wv = (const float*)d_in[3];
  const float* Wp = (const float*)d_in[4];
  const float* bp = (const float*)d_in[5];
  float* out = (float*)d_out;
  float* ws = (float*)d_ws;

  float* qws  = ws + OFF_Q;
  float* wtil = ws + OFF_WTIL;
  float* pmax = ws + OFF_PMAX;
  float* Lc   = ws + OFF_LC;
  float* ho4  = ws + OFF_HO4;
  float* y    = ws + OFF_Y;

  kq<<<dim3(16, NB), 256, 0, stream>>>(x, Wq, qws);
  kw<<<dim3(16, NB), 256, 0, stream>>>(Wk, qws, wtil);
  kF<<<dim3(NC, NB), 256, 0, stream>>>(x, wtil, y, pmax, Lc);
  k_comb<<<dim3(4, NH, NB), 256, 0, stream>>>(y, pmax, Lc, Wv, ho4);
  k_out<<<dim3(16, NB), 256, 0, stream>>>(ho4, Wp, bp, out);
}

// Round 7
// 517.502 us; speedup vs baseline: 1.8325x; 1.8325x over previous
//
#include <hip/hip_runtime.h>
#include <hip/hip_bf16.h>

#define NB 16
#define SEQ 4096
#define DIMC 1024
#define NH 16
#define DH 64
#define NC 64   // 64-row chunks per batch (kS / softmax stats)
#define RS 32   // row-splits for kY (128 rows = 2 chunks per block) -> 512 blocks = 2/CU

typedef short bf16x8 __attribute__((ext_vector_type(8)));
typedef float f32x4 __attribute__((ext_vector_type(4)));

// ws layout (floats):
#define OFF_Q    0            // [16][1024]            16384
#define OFF_WTIL 16384        // [16][16][1024]        262144
#define OFF_PMAX 278528       // [16][64][16]          16384
#define OFF_LC   294912       // [16][64][16]          16384
#define OFF_E    311296       // [16][4096][16]        1048576  (exp(S - m_chunk))
#define OFF_YOUT 1359872      // [16][32][16][1024]    8388608  (row-split partials of phat@x)
#define OFF_HO   9748480      // [16][1024]            16384
// total 9764864 floats = 39.1 MB

// ---------- kq: q[b][j] = x[b,0,:] . Wq[:,j]   (grid 16 jc x 16 b)
__global__ __launch_bounds__(256) void kq(const float* __restrict__ x,
                                          const float* __restrict__ Wq,
                                          float* __restrict__ qws) {
  const int jc = blockIdx.x, b = blockIdx.y, t = threadIdx.x;
  const int d = t & 63, g = t >> 6;
  const int j = jc * 64 + d;
  const float* x0 = x + (size_t)b * SEQ * DIMC;
  __shared__ float red[256];
  float a = 0.f;
  #pragma unroll 8
  for (int c = g * 256; c < g * 256 + 256; ++c)
    a = fmaf(x0[c], Wq[(size_t)c * DIMC + j], a);
  red[t] = a;
  __syncthreads();
  if (t < 64)
    qws[b * DIMC + jc * 64 + t] = red[t] + red[64 + t] + red[128 + t] + red[192 + t];
}

// ---------- kw: wtil[b][h][c] = 0.125 * Wk[c, h*64:h*64+64] . q[b, h*64:h*64+64]
// (RoPE cancels in q_rot . k_rot since both use the same per-head rotation.)
__global__ __launch_bounds__(256) void kw(const float* __restrict__ Wk,
                                          const float* __restrict__ qws,
                                          float* __restrict__ wtil) {
  const int cb = blockIdx.x, b = blockIdx.y, t = threadIdx.x;
  const int w = t >> 6, l = t & 63;
  float4 qreg[4];
  {
    const float4* q4 = (const float4*)(qws + b * DIMC + l * 16);
    #pragma unroll
    for (int i = 0; i < 4; ++i) qreg[i] = q4[i];
  }
  const int h = l >> 2;
  float* wt = wtil + ((size_t)b * NH + h) * DIMC;
  #pragma unroll 4
  for (int i = 0; i < 16; ++i) {
    const int c = cb * 64 + w * 16 + i;
    const float4* row = (const float4*)(Wk + (size_t)c * DIMC) + l * 4;
    float s = 0.f;
    #pragma unroll
    for (int k = 0; k < 4; ++k) {
      float4 rv = row[k];
      s = fmaf(rv.x, qreg[k].x, s); s = fmaf(rv.y, qreg[k].y, s);
      s = fmaf(rv.z, qreg[k].z, s); s = fmaf(rv.w, qreg[k].w, s);
    }
    s += __shfl_xor(s, 1);
    s += __shfl_xor(s, 2);
    if ((l & 3) == 0) wt[c] = s * 0.125f;
  }
}

// ---------- kS (MFMA): S = X @ wtil^T per 64-row chunk via mfma_f32_16x16x32_bf16.
// Block (nc, b), 4 waves; wave w owns rows nc*64+w*16 .. +15 (one 16x16 D tile, N=16 heads).
// A-frag: lane l holds x[r0 + (l&15)][kk*32 + (l>>4)*8 + j]  (8 consecutive f32 -> bf16).
// B-frag: lane l holds wtil_bf16[head = l&15][kk*32 + (l>>4)*8 + j] from padded LDS.
// D: lane l holds S[r0 + (l>>4)*4 + r][head = l&15]  (m89-verified C layout).
// Then chunk-local max/exp/sum per head (2 shfl + LDS cross-wave), write e/pmax/Lc (R5 iface).
__global__ __launch_bounds__(256) void kS(const float* __restrict__ x,
                                          const float* __restrict__ wtil,
                                          float* __restrict__ e,
                                          float* __restrict__ pmax,
                                          float* __restrict__ Lc) {
  const int nc = blockIdx.x, b = blockIdx.y, t = threadIdx.x;
  const int w = t >> 6, l = t & 63;
  __shared__ unsigned short wlds[16][1032];  // bf16 wtil, row padded +8 (33 KB)
  __shared__ float wred[4][16];

  // stage wtil (f32, includes 0.125 scale) -> bf16 LDS
  const float* wt = wtil + (size_t)b * NH * DIMC;
  for (int i = t; i < NH * DIMC; i += 256) {
    __hip_bfloat16 hb = __float2bfloat16(wt[i]);
    wlds[i >> 10][i & 1023] = *reinterpret_cast<unsigned short*>(&hb);
  }
  __syncthreads();

  const int lw = l & 15, lg = l >> 4;
  const int r0 = nc * 64 + w * 16;
  const float* xrow = x + ((size_t)b * SEQ + r0 + lw) * DIMC;

  f32x4 acc = {0.f, 0.f, 0.f, 0.f};
  #pragma unroll 4
  for (int kk = 0; kk < 32; ++kk) {
    const int k0 = kk * 32 + lg * 8;
    float4 a0 = *(const float4*)(xrow + k0);
    float4 a1 = *(const float4*)(xrow + k0 + 4);
    union { float4 v; float f[4]; } ua, ub;
    ua.v = a0; ub.v = a1;
    bf16x8 af;
    #pragma unroll
    for (int j = 0; j < 4; ++j) {
      __hip_bfloat16 h1 = __float2bfloat16(ua.f[j]);
      __hip_bfloat16 h2 = __float2bfloat16(ub.f[j]);
      af[j]     = (short)*reinterpret_cast<unsigned short*>(&h1);
      af[4 + j] = (short)*reinterpret_cast<unsigned short*>(&h2);
    }
    bf16x8 bfr = *(const bf16x8*)(&wlds[lw][k0]);
    acc = __builtin_amdgcn_mfma_f32_16x16x32_bf16(af, bfr, acc, 0, 0, 0);
  }

  // chunk-local stats per head (head = lw): lane holds rows lg*4 .. lg*4+3 (local)
  float m = fmaxf(fmaxf(acc[0], acc[1]), fmaxf(acc[2], acc[3]));
  m = fmaxf(m, __shfl_xor(m, 16));
  m = fmaxf(m, __shfl_xor(m, 32));          // wave-tile max for head lw
  if (l < 16) wred[w][l] = m;
  __syncthreads();
  const float mc = fmaxf(fmaxf(wred[0][lw], wred[1][lw]),
                         fmaxf(wred[2][lw], wred[3][lw]));  // chunk max
  float p0 = __expf(acc[0] - mc), p1 = __expf(acc[1] - mc);
  float p2 = __expf(acc[2] - mc), p3 = __expf(acc[3] - mc);
  float s = (p0 + p1) + (p2 + p3);
  s += __shfl_xor(s, 16);
  s += __shfl_xor(s, 32);                   // wave-tile sum for head lw
  __syncthreads();                          // before wred reuse
  if (l < 16) wred[w][l] = s;
  __syncthreads();

  // write e[(b, row, head)] = exp(S - m_chunk): rows r0 + lg*4 + r, head lw
  float* ep = e + ((size_t)b * SEQ + r0 + lg * 4) * NH + lw;
  ep[0 * NH] = p0; ep[1 * NH] = p1; ep[2 * NH] = p2; ep[3 * NH] = p3;

  if (w == 0 && l < 16) {
    float Ls = (wred[0][l] + wred[1][l]) + (wred[2][l] + wred[3][l]);
    pmax[((size_t)b * NC + nc) * NH + l] = mc;
    Lc  [((size_t)b * NC + nc) * NH + l] = Ls;
  }
}

// ---------- kY: global softmax scales + row-split partial of phat @ x.
// Block (rs, b) covers rows rs*128..rs*128+127 (2 chunks). Thread t owns col-quad t.
__global__ __launch_bounds__(256) void kY(const float* __restrict__ x,
                                          const float* __restrict__ e,
                                          const float* __restrict__ pmax,
                                          const float* __restrict__ Lc,
                                          float* __restrict__ yout) {
  const int rs = blockIdx.x, b = blockIdx.y, t = threadIdx.x;
  __shared__ float4 sc4[NC][4];  // [chunk][head-quad] : exp(m_ch - M)/L
  __shared__ float4 pl[64][4];   // staged phat rows for current chunk

  if (t < 64) {  // wave 0: lane = chunk
    const int ch = t;
    float scl[16];
    #pragma unroll
    for (int h = 0; h < 16; ++h) {
      float m  = pmax[((size_t)b * NC + ch) * NH + h];
      float lc = Lc[((size_t)b * NC + ch) * NH + h];
      float M = m;
      #pragma unroll
      for (int o = 1; o < 64; o <<= 1) M = fmaxf(M, __shfl_xor(M, o));
      float ex = __expf(m - M);
      float lw = lc * ex;
      #pragma unroll
      for (int o = 1; o < 64; o <<= 1) lw += __shfl_xor(lw, o);
      scl[h] = ex / lw;
    }
    #pragma unroll
    for (int q = 0; q < 4; ++q)
      sc4[ch][q] = make_float4(scl[4 * q], scl[4 * q + 1], scl[4 * q + 2], scl[4 * q + 3]);
  }

  const float4* x4 = (const float4*)x + (size_t)b * SEQ * 256;
  const float4* e4 = (const float4*)e + (size_t)b * SEQ * 4;

  float4 acc[16];
  #pragma unroll
  for (int h = 0; h < 16; ++h) acc[h] = make_float4(0.f, 0.f, 0.f, 0.f);

  for (int c4 = 0; c4 < 2; ++c4) {
    const int ch = rs * 2 + c4;
    __syncthreads();  // protect sc4 (first iter) / pl readers (later iters)
    {
      const int r = t >> 2, qd = t & 3;
      float4 ev = e4[(size_t)(ch * 64 + r) * 4 + qd];
      float4 s  = sc4[ch][qd];
      pl[r][qd] = make_float4(ev.x * s.x, ev.y * s.y, ev.z * s.z, ev.w * s.w);
    }
    __syncthreads();

    const float4* xc = x4 + (size_t)(ch * 64) * 256;
    for (int r = 0; r < 64; r += 4) {
      float4 xv0 = xc[(size_t)(r + 0) * 256 + t];
      float4 xv1 = xc[(size_t)(r + 1) * 256 + t];
      float4 xv2 = xc[(size_t)(r + 2) * 256 + t];
      float4 xv3 = xc[(size_t)(r + 3) * 256 + t];
      #pragma unroll
      for (int rr = 0; rr < 4; ++rr) {
        float4 xv = (rr == 0) ? xv0 : (rr == 1) ? xv1 : (rr == 2) ? xv2 : xv3;
        float4 p0 = pl[r + rr][0], p1 = pl[r + rr][1];
        float4 p2 = pl[r + rr][2], p3 = pl[r + rr][3];
        #define ACC(h, ev) acc[h].x = fmaf(ev, xv.x, acc[h].x); acc[h].y = fmaf(ev, xv.y, acc[h].y); \
                           acc[h].z = fmaf(ev, xv.z, acc[h].z); acc[h].w = fmaf(ev, xv.w, acc[h].w)
        ACC(0, p0.x); ACC(1, p0.y); ACC(2, p0.z); ACC(3, p0.w);
        ACC(4, p1.x); ACC(5, p1.y); ACC(6, p1.z); ACC(7, p1.w);
        ACC(8, p2.x); ACC(9, p2.y); ACC(10, p2.z); ACC(11, p2.w);
        ACC(12, p3.x); ACC(13, p3.y); ACC(14, p3.z); ACC(15, p3.w);
        #undef ACC
      }
    }
  }

  float4* yo = (float4*)yout + (((size_t)b * RS + rs) * NH) * 256 + t;
  #pragma unroll
  for (int h = 0; h < 16; ++h) yo[h * 256] = acc[h];
}

// ---------- kV: ho[b][h*64+d] = (sum_rs yout[b][rs][h][:]) . Wv[:, h*64+d]
__global__ __launch_bounds__(256) void kV(const float* __restrict__ yout,
                                          const float* __restrict__ Wv,
                                          float* __restrict__ ho) {
  const int cq = blockIdx.x, h = blockIdx.y, b = blockIdx.z, t = threadIdx.x;
  __shared__ float ysum[DIMC];
  __shared__ float red[256];
  #pragma unroll
  for (int i = 0; i < 4; ++i) {
    const int c = i * 256 + t;
    float s = 0.f;
    #pragma unroll 8
    for (int r = 0; r < RS; ++r)
      s += yout[(((size_t)b * RS + r) * NH + h) * DIMC + c];
    ysum[c] = s;
  }
  __syncthreads();
  const int d = t & 15, g = t >> 4;
  float a = 0.f;
  #pragma unroll 8
  for (int i = 0; i < 64; ++i)
    a = fmaf(ysum[g * 64 + i], Wv[(size_t)(g * 64 + i) * DIMC + h * DH + cq * 16 + d], a);
  red[t] = a;
  __syncthreads();
  if (t < 16) {
    float s = 0.f;
    #pragma unroll
    for (int j = 0; j < 16; ++j) s += red[j * 16 + t];
    ho[(size_t)b * DIMC + h * DH + cq * 16 + t] = s;
  }
}

// ---------- k_out: out[b, j] = ho[b,:] . Wp[:, j] + bp[j]
__global__ __launch_bounds__(256) void k_out(const float* __restrict__ ho,
                                             const float* __restrict__ Wp,
                                             const float* __restrict__ bp,
                                             float* __restrict__ out) {
  const int jc = blockIdx.x, b = blockIdx.y, t = threadIdx.x;
  __shared__ float hs[1024];
  __shared__ float red[256];
  for (int i = t; i < 1024; i += 256)
    hs[i] = ho[(size_t)b * DIMC + i];
  __syncthreads();
  const int d = t & 63, g = t >> 6;
  const int j = jc * 64 + d;
  float a = 0.f;
  #pragma unroll 8
  for (int i = g * 256; i < g * 256 + 256; ++i)
    a = fmaf(hs[i], Wp[(size_t)i * DIMC + j], a);
  red[t] = a;
  __syncthreads();
  if (t < 64)
    out[(size_t)b * DIMC + jc * 64 + t] =
        red[t] + red[64 + t] + red[128 + t] + red[192 + t] + bp[jc * 64 + t];
}

extern "C" void kernel_launch(void* const* d_in, const int* in_sizes, int n_in,
                              void* d_out, int out_size, void* d_ws, size_t ws_size,
                              hipStream_t stream) {
  const float* x  = (const float*)d_in[0];
  const float* Wq = (const float*)d_in[1];
  const float* Wk = (const float*)d_in[2];
  const float* Wv = (const float*)d_in[3];
  const float* Wp = (const float*)d_in[4];
  const float* bp = (const float*)d_in[5];
  float* out = (float*)d_out;
  float* ws = (float*)d_ws;

  float* qws  = ws + OFF_Q;
  float* wtil = ws + OFF_WTIL;
  float* pmax = ws + OFF_PMAX;
  float* Lc   = ws + OFF_LC;
  float* e    = ws + OFF_E;
  float* yout = ws + OFF_YOUT;
  float* ho   = ws + OFF_HO;

  kq<<<dim3(16, NB), 256, 0, stream>>>(x, Wq, qws);
  kw<<<dim3(16, NB), 256, 0, stream>>>(Wk, qws, wtil);
  kS<<<dim3(NC, NB), 256, 0, stream>>>(x, wtil, e, pmax, Lc);
  kY<<<dim3(RS, NB), 256, 0, stream>>>(x, e, pmax, Lc, yout);
  kV<<<dim3(4, NH, NB), 256, 0, stream>>>(yout, Wv, ho);
  k_out<<<dim3(16, NB), 256, 0, stream>>>(ho, Wp, bp, out);
}